// Round 1
// baseline (774.430 us; speedup 1.0000x reference)
//
#include <hip/hip_runtime.h>
#include <cstdint>
#include <cstddef>

typedef float f4 __attribute__((ext_vector_type(4)));

#define B_   32
#define C_   768
#define HW_  1024
#define DQ_  16
#define K_   64
#define M_   1024   // K_*DQ_

// ---- K1 tiling ----
#define BM   256    // kq rows per block
#define BN   64     // hw cols per block
#define BC   32     // c chunk
#define NMT  4      // M_/BM
#define NHWT 16     // HW_/BN

#define CODE_OFF 524288
#define LOSS_OFF 524320

// ============================================================
// K1: fused kv-GEMM + squared-distance partial reduction.
// grid (NMT, NHWT, B_), block 256.
// partial[b][k][hwt] = sum over (q, hw in tile) of (query - kv)^2
// ============================================================
__global__ __launch_bounds__(256)
void k1_dist(const float* __restrict__ Fp, const float* __restrict__ Qp,
             const float* __restrict__ Wp, float* __restrict__ partial)
{
    __shared__ float w_lds[BC][BM];   // 32 KB, [c][m] (transposed on stage)
    __shared__ float f_lds[BC][BN];   // 8 KB,  [c][hw]
    __shared__ float red[32][8];      // 1 KB epilogue reduce

    const int tid = threadIdx.x;
    const int mt  = blockIdx.x;
    const int hwt = blockIdx.y;
    const int b   = blockIdx.z;
    const int ty  = tid >> 3;     // 0..31  (M direction, 8 m each)
    const int tx  = tid & 7;      // 0..7   (N direction, 8 hw each)
    const int m0  = ty * 8;
    const int hw0 = tx * 8;

    float acc[8][8];
#pragma unroll
    for (int i = 0; i < 8; ++i)
#pragma unroll
        for (int j = 0; j < 8; ++j) acc[i][j] = 0.f;

    for (int c0 = 0; c0 < C_; c0 += BC) {
        // ---- stage W chunk, transpose [m][c] -> [c][m] ----
        // global: coalesced (8 lanes x 16B contiguous per m-row)
#pragma unroll
        for (int i = 0; i < 8; ++i) {
            const int m_l = i * 32 + ty;
            const int c_l = tx * 4;
            f4 w4 = *(const f4*)&Wp[(size_t)(mt * BM + m_l) * C_ + c0 + c_l];
            w_lds[c_l + 0][m_l] = w4.x;
            w_lds[c_l + 1][m_l] = w4.y;
            w_lds[c_l + 2][m_l] = w4.z;
            w_lds[c_l + 3][m_l] = w4.w;
        }
        // ---- stage features chunk [c][hw], linear, coalesced ----
        {
            const int c  = tid >> 3;        // 0..31
            const int hw = (tid & 7) * 8;   // 0..56
            const float* src = &Fp[((size_t)b * C_ + c0 + c) * HW_ + (size_t)hwt * BN + hw];
            f4 a0 = *(const f4*)src;
            f4 a1 = *(const f4*)(src + 4);
            *(f4*)&f_lds[c][hw]     = a0;
            *(f4*)&f_lds[c][hw + 4] = a1;
        }
        __syncthreads();

#pragma unroll 4
        for (int cc = 0; cc < BC; ++cc) {
            f4 w0 = *(const f4*)&w_lds[cc][m0];
            f4 w1 = *(const f4*)&w_lds[cc][m0 + 4];
            f4 g0 = *(const f4*)&f_lds[cc][hw0];
            f4 g1 = *(const f4*)&f_lds[cc][hw0 + 4];
            const float wa[8] = {w0.x, w0.y, w0.z, w0.w, w1.x, w1.y, w1.z, w1.w};
            const float fv[8] = {g0.x, g0.y, g0.z, g0.w, g1.x, g1.y, g1.z, g1.w};
#pragma unroll
            for (int i = 0; i < 8; ++i)
#pragma unroll
                for (int j = 0; j < 8; ++j)
                    acc[i][j] = fmaf(wa[i], fv[j], acc[i][j]);
        }
        __syncthreads();
    }

    // ---- epilogue: (q - kv)^2, reduce to per-(k, hw-tile) partial ----
    // thread's 8 m-rows lie inside ONE k: k = mt*16 + ty/2, q = (ty&1)*8 + i
    const int q0 = (ty & 1) * 8;
    float s = 0.f;
#pragma unroll
    for (int i = 0; i < 8; ++i) {
        const float* qp = &Qp[((size_t)b * DQ_ + q0 + i) * HW_ + (size_t)hwt * BN + hw0];
        f4 qa = *(const f4*)qp;
        f4 qb = *(const f4*)(qp + 4);
        float d;
        d = qa.x - acc[i][0]; s = fmaf(d, d, s);
        d = qa.y - acc[i][1]; s = fmaf(d, d, s);
        d = qa.z - acc[i][2]; s = fmaf(d, d, s);
        d = qa.w - acc[i][3]; s = fmaf(d, d, s);
        d = qb.x - acc[i][4]; s = fmaf(d, d, s);
        d = qb.y - acc[i][5]; s = fmaf(d, d, s);
        d = qb.z - acc[i][6]; s = fmaf(d, d, s);
        d = qb.w - acc[i][7]; s = fmaf(d, d, s);
    }
    red[ty][tx] = s;
    __syncthreads();
    if (tid < 16) {
        float t = 0.f;
#pragma unroll
        for (int r = 0; r < 2; ++r)
#pragma unroll
            for (int x = 0; x < 8; ++x)
                t += red[tid * 2 + r][x];
        partial[((size_t)b * K_ + mt * 16 + tid) * NHWT + hwt] = t;
    }
}

// ============================================================
// K2: reduce partials -> dist2[b][k], argmin (first-min tie-break),
// write codes (as float) + commit_loss. One block, 1024 threads.
// ============================================================
__global__ __launch_bounds__(1024)
void k2_select(const float* __restrict__ partial, float* __restrict__ out,
               int* __restrict__ codes_ws)
{
    const int tid = threadIdx.x;
    const int b  = tid >> 5;   // 0..31
    const int kk = tid & 31;   // 0..31 ; thread handles k = kk and kk+32
    float s0 = 0.f, s1 = 0.f;
#pragma unroll
    for (int h = 0; h < NHWT; ++h) {
        s0 += partial[((size_t)b * K_ + kk) * NHWT + h];
        s1 += partial[((size_t)b * K_ + kk + 32) * NHWT + h];
    }
    float bv = s0; int bk = kk;
    if (s1 < bv) { bv = s1; bk = kk + 32; }
    // reduce across the 32 lanes of this b (lanes stay in half-wave for mask<32)
#pragma unroll
    for (int m = 16; m >= 1; m >>= 1) {
        float ov = __shfl_xor(bv, m);
        int   ok = __shfl_xor(bk, m);
        if (ov < bv || (ov == bv && ok < bk)) { bv = ov; bk = ok; }
    }
    __shared__ float mins[32];
    if (kk == 0) {
        out[CODE_OFF + b] = (float)bk;
        codes_ws[b] = bk;
        mins[b] = bv;
    }
    __syncthreads();
    if (tid == 0) {
        float t = 0.f;
#pragma unroll
        for (int i = 0; i < 32; ++i) t += mins[i];
        out[LOSS_OFF] = t * (1.0f / 524288.0f);  // mean over B*DQ*H*W
    }
}

// ============================================================
// K3: sel[b,q,hw] = sum_c W[code_b,q,c] * F[b,c,hw]  (fp32 exact recompute)
// grid = B_*8 blocks (128 hw per block), block 256 = 16q x 16 hw-groups.
// ============================================================
#define BN3 128
#define BC3 32

__global__ __launch_bounds__(256)
void k3_sel(const float* __restrict__ Fp, const float* __restrict__ Wp,
            const int* __restrict__ codes_ws, float* __restrict__ out)
{
    __shared__ float f_lds[BC3][BN3];  // 16 KB
    __shared__ float w_lds[DQ_][33];   // padded

    const int tid = threadIdx.x;
    const int b   = blockIdx.x >> 3;
    const int hwt = blockIdx.x & 7;
    const int code = codes_ws[b];
    const int q   = tid >> 4;          // 0..15
    const int hw0 = (tid & 15) * 8;    // 0..120

    float a[8] = {0.f,0.f,0.f,0.f,0.f,0.f,0.f,0.f};

    for (int c0 = 0; c0 < C_; c0 += BC3) {
        if (tid < 128) {
            const int qq = tid >> 3, c4 = (tid & 7) * 4;
            f4 w4 = *(const f4*)&Wp[((size_t)code * DQ_ + qq) * C_ + c0 + c4];
            w_lds[qq][c4 + 0] = w4.x;
            w_lds[qq][c4 + 1] = w4.y;
            w_lds[qq][c4 + 2] = w4.z;
            w_lds[qq][c4 + 3] = w4.w;
        }
        {
            const int c  = tid >> 3;          // 0..31
            const int hw = (tid & 7) * 16;    // 0..112
            const float* src = &Fp[((size_t)b * C_ + c0 + c) * HW_ + (size_t)hwt * BN3 + hw];
            f4 v0 = *(const f4*)(src);
            f4 v1 = *(const f4*)(src + 4);
            f4 v2 = *(const f4*)(src + 8);
            f4 v3 = *(const f4*)(src + 12);
            *(f4*)&f_lds[c][hw]      = v0;
            *(f4*)&f_lds[c][hw + 4]  = v1;
            *(f4*)&f_lds[c][hw + 8]  = v2;
            *(f4*)&f_lds[c][hw + 12] = v3;
        }
        __syncthreads();
#pragma unroll 4
        for (int cc = 0; cc < BC3; ++cc) {
            const float wv = w_lds[q][cc];
            f4 g0 = *(const f4*)&f_lds[cc][hw0];
            f4 g1 = *(const f4*)&f_lds[cc][hw0 + 4];
            a[0] = fmaf(wv, g0.x, a[0]);
            a[1] = fmaf(wv, g0.y, a[1]);
            a[2] = fmaf(wv, g0.z, a[2]);
            a[3] = fmaf(wv, g0.w, a[3]);
            a[4] = fmaf(wv, g1.x, a[4]);
            a[5] = fmaf(wv, g1.y, a[5]);
            a[6] = fmaf(wv, g1.z, a[6]);
            a[7] = fmaf(wv, g1.w, a[7]);
        }
        __syncthreads();
    }

    float* dst = &out[((size_t)b * DQ_ + q) * HW_ + (size_t)hwt * BN3 + hw0];
    f4 o0 = {a[0], a[1], a[2], a[3]};
    f4 o1 = {a[4], a[5], a[6], a[7]};
    *(f4*)dst       = o0;
    *(f4*)(dst + 4) = o1;
}

// ============================================================
extern "C" void kernel_launch(void* const* d_in, const int* in_sizes, int n_in,
                              void* d_out, int out_size, void* d_ws, size_t ws_size,
                              hipStream_t stream)
{
    const float* Fp = (const float*)d_in[0];  // features [B,C,H,W]
    const float* Qp = (const float*)d_in[1];  // query    [B,DQ,H,W]
    const float* Wp = (const float*)d_in[2];  // W        [K,DQ,C]
    float* out = (float*)d_out;

    float* partial  = (float*)d_ws;                                        // B*K*NHWT floats (128 KB)
    int*   codes_ws = (int*)((char*)d_ws + (size_t)B_ * K_ * NHWT * 4);    // 32 ints

    k1_dist<<<dim3(NMT, NHWT, B_), 256, 0, stream>>>(Fp, Qp, Wp, partial);
    k2_select<<<1, 1024, 0, stream>>>(partial, out, codes_ws);
    k3_sel<<<dim3(B_ * 8), 256, 0, stream>>>(Fp, Wp, codes_ws, out);
}

// Round 2
// 378.223 us; speedup vs baseline: 2.0475x; 2.0475x over previous
//
#include <hip/hip_runtime.h>
#include <cstdint>
#include <cstddef>

typedef float f4 __attribute__((ext_vector_type(4)));
typedef float f32x4 __attribute__((ext_vector_type(4)));
typedef short short8 __attribute__((ext_vector_type(8)));
typedef unsigned short u16x8 __attribute__((ext_vector_type(8)));
typedef unsigned short u16x4 __attribute__((ext_vector_type(4)));
typedef unsigned short ushort_t;

#define B_   32
#define C_   768
#define HW_  1024
#define DQ_  16
#define K_   64
#define M_   1024
#define NHWT 16

#define CODE_OFF 524288
#define LOSS_OFF 524320

// ---------------- bf16 split helpers (RNE) ----------------
__device__ __forceinline__ unsigned bf16_rne_bits(float x) {
    unsigned u = __builtin_bit_cast(unsigned, x);
    return (u + 0x7FFFu + ((u >> 16) & 1u)) >> 16;
}
__device__ __forceinline__ float bits_to_f32(unsigned hi16) {
    unsigned u = hi16 << 16;
    return __builtin_bit_cast(float, u);
}
__device__ __forceinline__ void split_bf16(float x, unsigned short& hi, unsigned short& lo) {
    unsigned h = bf16_rne_bits(x);
    hi = (unsigned short)h;
    float r = x - bits_to_f32(h);
    lo = (unsigned short)bf16_rne_bits(r);
}

// ============================================================
// K0a: split + transpose features: F[b][c][hw] fp32 ->
//      FhiT/FloT [b][hw][c] bf16.  grid (16 hw-tiles, 12 c-tiles, B)
// ============================================================
__global__ __launch_bounds__(256)
void k0_splitF(const float* __restrict__ Fp,
               ushort_t* __restrict__ FhiT, ushort_t* __restrict__ FloT)
{
    __shared__ float tile[64][65];
    const int t = threadIdx.x;
    const int ht = blockIdx.x, ct = blockIdx.y, b = blockIdx.z;

#pragma unroll
    for (int rep = 0; rep < 4; ++rep) {
        int idx = rep * 256 + t;
        int c_l = idx >> 4;             // 0..63
        int hwf = (idx & 15) * 4;       // 0..60
        f4 v = *(const f4*)&Fp[((size_t)b * C_ + ct * 64 + c_l) * HW_ + ht * 64 + hwf];
        tile[c_l][hwf + 0] = v.x;
        tile[c_l][hwf + 1] = v.y;
        tile[c_l][hwf + 2] = v.z;
        tile[c_l][hwf + 3] = v.w;
    }
    __syncthreads();

#pragma unroll
    for (int rep = 0; rep < 2; ++rep) {
        int hw_l = (t >> 3) + rep * 32;   // 0..63
        int cg   = (t & 7) * 8;           // 0..56
        unsigned short hi[8], lo[8];
#pragma unroll
        for (int j = 0; j < 8; ++j)
            split_bf16(tile[cg + j][hw_l], hi[j], lo[j]);
        size_t o = ((size_t)b * HW_ + ht * 64 + hw_l) * C_ + ct * 64 + cg;
        *(u16x8*)&FhiT[o] = *(u16x8*)hi;
        *(u16x8*)&FloT[o] = *(u16x8*)lo;
    }
}

// ============================================================
// K0b: split W: [1024][768] fp32 -> Whi/Wlo bf16 (same layout)
// ============================================================
__global__ __launch_bounds__(256)
void k0_splitW(const float* __restrict__ Wp,
               ushort_t* __restrict__ Whi, ushort_t* __restrict__ Wlo)
{
    size_t base = ((size_t)blockIdx.x * 256 + threadIdx.x) * 4;
    f4 v = *(const f4*)&Wp[base];
    unsigned short hi[4], lo[4];
    split_bf16(v.x, hi[0], lo[0]);
    split_bf16(v.y, hi[1], lo[1]);
    split_bf16(v.z, hi[2], lo[2]);
    split_bf16(v.w, hi[3], lo[3]);
    *(u16x4*)&Whi[base] = *(u16x4*)hi;
    *(u16x4*)&Wlo[base] = *(u16x4*)lo;
}

// ============================================================
// K1: bf16-triple MFMA GEMM + fused distance epilogue.
// grid (8 mt, 8 hwt, B), 256 threads = 4 waves (2x2).
// Tile: 128 m x 128 hw, BK=32, single-buffered LDS, m97 structure.
// acc = Whi*Fhi + Whi*Flo + Wlo*Fhi  (fp32 MFMA accum)
// partial[b][k][hwt*2+wn] = sum (Q - kv)^2 over the 64-hw x 16-q chunk
// ============================================================
__global__ __launch_bounds__(256)
void k1_mfma(const ushort_t* __restrict__ Whi, const ushort_t* __restrict__ Wlo,
             const ushort_t* __restrict__ FhiT, const ushort_t* __restrict__ FloT,
             const float* __restrict__ Qp, float* __restrict__ partial)
{
    __shared__ ushort_t lds[4][128 * 32];   // Ahi, Alo, Bhi, Blo (8 KB each)

    const int tid  = threadIdx.x;
    const int wid  = tid >> 6;
    const int lane = tid & 63;
    const int mt = blockIdx.x, hwt = blockIdx.y, b = blockIdx.z;
    const int wm = wid >> 1, wn = wid & 1;

    f32x4 acc[4][4] = {};

    // per-wave staging source (wave w stages tile w)
    const ushort_t* srcp;
    size_t rowbase;
    if (wid == 0)      { srcp = Whi;  rowbase = (size_t)(mt * 128) * C_; }
    else if (wid == 1) { srcp = Wlo;  rowbase = (size_t)(mt * 128) * C_; }
    else if (wid == 2) { srcp = FhiT; rowbase = ((size_t)b * HW_ + hwt * 128) * C_; }
    else               { srcp = FloT; rowbase = ((size_t)b * HW_ + hwt * 128) * C_; }

    const int rl   = lane >> 2;   // row-within-16 per staging instr
    const int slot = lane & 3;
    ushort_t* mytile = &lds[wid][0];

    // frag read offsets (lane-constant): swizzled ds_read addresses
    const int s16 = lane >> 4, c15 = lane & 15;
    int offA[4], offB[4];
#pragma unroll
    for (int i = 0; i < 4; ++i) {
        int ra = wm * 64 + i * 16 + c15;
        offA[i] = ra * 32 + ((s16 ^ ((ra >> 1) & 3)) << 3);
        int rb = wn * 64 + i * 16 + c15;
        offB[i] = rb * 32 + ((s16 ^ ((rb >> 1) & 3)) << 3);
    }

    for (int c0 = 0; c0 < C_; c0 += 32) {
        // ---- stage this wave's 8KB tile: 8 x global_load_lds(16B) ----
#pragma unroll
        for (int ii = 0; ii < 8; ++ii) {
            int r = ii * 16 + rl;
            int g = slot ^ ((r >> 1) & 3);           // pre-swizzled global source
            const ushort_t* src = srcp + rowbase + (size_t)r * C_ + c0 + g * 8;
            __builtin_amdgcn_global_load_lds(
                (const __attribute__((address_space(1))) void*)src,
                (__attribute__((address_space(3))) void*)(mytile + ii * 512),
                16, 0, 0);
        }
        __syncthreads();

        short8 ah[4], al[4], bh[4], bl[4];
#pragma unroll
        for (int i = 0; i < 4; ++i) {
            ah[i] = *(const short8*)&lds[0][offA[i]];
            al[i] = *(const short8*)&lds[1][offA[i]];
            bh[i] = *(const short8*)&lds[2][offB[i]];
            bl[i] = *(const short8*)&lds[3][offB[i]];
        }
#pragma unroll
        for (int i = 0; i < 4; ++i)
#pragma unroll
            for (int j = 0; j < 4; ++j) {
                acc[i][j] = __builtin_amdgcn_mfma_f32_16x16x32_bf16(ah[i], bh[j], acc[i][j], 0, 0, 0);
                acc[i][j] = __builtin_amdgcn_mfma_f32_16x16x32_bf16(ah[i], bl[j], acc[i][j], 0, 0, 0);
                acc[i][j] = __builtin_amdgcn_mfma_f32_16x16x32_bf16(al[i], bh[j], acc[i][j], 0, 0, 0);
            }
        __syncthreads();
    }

    // ---- epilogue: (Q - kv)^2, reduce per fragment-row (= per k) ----
    // C/D: col = lane&15 (hw), row = (lane>>4)*4 + reg (= q, since each
    // 16-row fragment spans exactly one k).
    float qv[4][4];
#pragma unroll
    for (int j = 0; j < 4; ++j) {
        int hw = hwt * 128 + wn * 64 + j * 16 + c15;
#pragma unroll
        for (int rr = 0; rr < 4; ++rr) {
            int q = s16 * 4 + rr;
            qv[j][rr] = Qp[((size_t)(b * DQ_ + q)) * HW_ + hw];
        }
    }
#pragma unroll
    for (int i = 0; i < 4; ++i) {
        float ssum = 0.f;
#pragma unroll
        for (int j = 0; j < 4; ++j)
#pragma unroll
            for (int rr = 0; rr < 4; ++rr) {
                float d = qv[j][rr] - acc[i][j][rr];
                ssum = fmaf(d, d, ssum);
            }
#pragma unroll
        for (int off = 32; off; off >>= 1) ssum += __shfl_xor(ssum, off);
        if (lane == 0) {
            int k = mt * 8 + wm * 4 + i;
            partial[(((size_t)b * K_ + k) << 4) + hwt * 2 + wn] = ssum;
        }
    }
}

// ============================================================
// K1 fallback (fp32 VALU, bank-conflict-fixed) if ws too small
// ============================================================
#define BM   256
#define BN   64
#define BC   32
#define NMT  4

__global__ __launch_bounds__(256)
void k1_dist_fp32(const float* __restrict__ Fp, const float* __restrict__ Qp,
                  const float* __restrict__ Wp, float* __restrict__ partial)
{
    __shared__ float w_lds[BC][BM];     // swizzled: col = m ^ (4*((c>>2)&7))
    __shared__ float f_lds[BC][BN + 8]; // padded
    __shared__ float red[32][8];

    const int tid = threadIdx.x;
    const int mt = blockIdx.x, hwt = blockIdx.y, b = blockIdx.z;
    const int ty = tid >> 3, tx = tid & 7;
    const int m0 = ty * 8, hw0 = tx * 8;

    float acc[8][8];
#pragma unroll
    for (int i = 0; i < 8; ++i)
#pragma unroll
        for (int j = 0; j < 8; ++j) acc[i][j] = 0.f;

    for (int c0 = 0; c0 < C_; c0 += BC) {
#pragma unroll
        for (int i = 0; i < 8; ++i) {
            const int m_l = i * 32 + ty;
            const int c_l = tx * 4;
            const int col = m_l ^ (tx * 4);
            f4 w4 = *(const f4*)&Wp[(size_t)(mt * BM + m_l) * C_ + c0 + c_l];
            w_lds[c_l + 0][col] = w4.x;
            w_lds[c_l + 1][col] = w4.y;
            w_lds[c_l + 2][col] = w4.z;
            w_lds[c_l + 3][col] = w4.w;
        }
        {
            const int c = tid >> 3;
            const int hw = (tid & 7) * 8;
            const float* src = &Fp[((size_t)b * C_ + c0 + c) * HW_ + (size_t)hwt * BN + hw];
            *(f4*)&f_lds[c][hw]     = *(const f4*)src;
            *(f4*)&f_lds[c][hw + 4] = *(const f4*)(src + 4);
        }
        __syncthreads();

#pragma unroll 4
        for (int cc = 0; cc < BC; ++cc) {
            const int sw = ((cc >> 2) & 7) * 4;
            const int colA = m0 ^ sw;
            f4 w0 = *(const f4*)&w_lds[cc][colA];
            f4 w1 = *(const f4*)&w_lds[cc][colA ^ 4];
            f4 g0 = *(const f4*)&f_lds[cc][hw0];
            f4 g1 = *(const f4*)&f_lds[cc][hw0 + 4];
            const float wa[8] = {w0.x, w0.y, w0.z, w0.w, w1.x, w1.y, w1.z, w1.w};
            const float fv[8] = {g0.x, g0.y, g0.z, g0.w, g1.x, g1.y, g1.z, g1.w};
#pragma unroll
            for (int i = 0; i < 8; ++i)
#pragma unroll
                for (int j = 0; j < 8; ++j)
                    acc[i][j] = fmaf(wa[i], fv[j], acc[i][j]);
        }
        __syncthreads();
    }

    const int q0 = (ty & 1) * 8;
    float s = 0.f;
#pragma unroll
    for (int i = 0; i < 8; ++i) {
        const float* qp = &Qp[((size_t)b * DQ_ + q0 + i) * HW_ + (size_t)hwt * BN + hw0];
        f4 qa = *(const f4*)qp;
        f4 qb = *(const f4*)(qp + 4);
        float d;
        d = qa.x - acc[i][0]; s = fmaf(d, d, s);
        d = qa.y - acc[i][1]; s = fmaf(d, d, s);
        d = qa.z - acc[i][2]; s = fmaf(d, d, s);
        d = qa.w - acc[i][3]; s = fmaf(d, d, s);
        d = qb.x - acc[i][4]; s = fmaf(d, d, s);
        d = qb.y - acc[i][5]; s = fmaf(d, d, s);
        d = qb.z - acc[i][6]; s = fmaf(d, d, s);
        d = qb.w - acc[i][7]; s = fmaf(d, d, s);
    }
    red[ty][tx] = s;
    __syncthreads();
    if (tid < 16) {
        float t = 0.f;
#pragma unroll
        for (int r = 0; r < 2; ++r)
#pragma unroll
            for (int x = 0; x < 8; ++x) t += red[tid * 2 + r][x];
        partial[((size_t)b * K_ + mt * 16 + tid) * NHWT + hwt] = t;
    }
}

// ============================================================
// K2: reduce partials -> argmin + loss
// ============================================================
__global__ __launch_bounds__(1024)
void k2_select(const float* __restrict__ partial, float* __restrict__ out,
               int* __restrict__ codes_ws)
{
    const int tid = threadIdx.x;
    const int b = tid >> 5, kk = tid & 31;
    float s0 = 0.f, s1 = 0.f;
#pragma unroll
    for (int h = 0; h < NHWT; ++h) {
        s0 += partial[((size_t)b * K_ + kk) * NHWT + h];
        s1 += partial[((size_t)b * K_ + kk + 32) * NHWT + h];
    }
    float bv = s0; int bk = kk;
    if (s1 < bv) { bv = s1; bk = kk + 32; }
#pragma unroll
    for (int m = 16; m >= 1; m >>= 1) {
        float ov = __shfl_xor(bv, m);
        int   ok = __shfl_xor(bk, m);
        if (ov < bv || (ov == bv && ok < bk)) { bv = ov; bk = ok; }
    }
    __shared__ float mins[32];
    if (kk == 0) {
        out[CODE_OFF + b] = (float)bk;
        codes_ws[b] = bk;
        mins[b] = bv;
    }
    __syncthreads();
    if (tid == 0) {
        float t = 0.f;
#pragma unroll
        for (int i = 0; i < 32; ++i) t += mins[i];
        out[LOSS_OFF] = t * (1.0f / 524288.0f);
    }
}

// ============================================================
// K3: exact fp32 recompute of sel for the chosen code
// ============================================================
#define BN3 128
#define BC3 32

__global__ __launch_bounds__(256)
void k3_sel(const float* __restrict__ Fp, const float* __restrict__ Wp,
            const int* __restrict__ codes_ws, float* __restrict__ out)
{
    __shared__ float f_lds[BC3][BN3];
    __shared__ float w_lds[DQ_][33];

    const int tid = threadIdx.x;
    const int b = blockIdx.x >> 3, hwt = blockIdx.x & 7;
    const int code = codes_ws[b];
    const int q = tid >> 4;
    const int hw0 = (tid & 15) * 8;

    float a[8] = {0.f, 0.f, 0.f, 0.f, 0.f, 0.f, 0.f, 0.f};

    for (int c0 = 0; c0 < C_; c0 += BC3) {
        if (tid < 128) {
            const int qq = tid >> 3, c4 = (tid & 7) * 4;
            f4 w4 = *(const f4*)&Wp[((size_t)code * DQ_ + qq) * C_ + c0 + c4];
            w_lds[qq][c4 + 0] = w4.x;
            w_lds[qq][c4 + 1] = w4.y;
            w_lds[qq][c4 + 2] = w4.z;
            w_lds[qq][c4 + 3] = w4.w;
        }
        {
            const int c = tid >> 3;
            const int hw = (tid & 7) * 16;
            const float* src = &Fp[((size_t)b * C_ + c0 + c) * HW_ + (size_t)hwt * BN3 + hw];
            *(f4*)&f_lds[c][hw]      = *(const f4*)(src);
            *(f4*)&f_lds[c][hw + 4]  = *(const f4*)(src + 4);
            *(f4*)&f_lds[c][hw + 8]  = *(const f4*)(src + 8);
            *(f4*)&f_lds[c][hw + 12] = *(const f4*)(src + 12);
        }
        __syncthreads();
#pragma unroll 4
        for (int cc = 0; cc < BC3; ++cc) {
            const float wv = w_lds[q][cc];
            f4 g0 = *(const f4*)&f_lds[cc][hw0];
            f4 g1 = *(const f4*)&f_lds[cc][hw0 + 4];
            a[0] = fmaf(wv, g0.x, a[0]);
            a[1] = fmaf(wv, g0.y, a[1]);
            a[2] = fmaf(wv, g0.z, a[2]);
            a[3] = fmaf(wv, g0.w, a[3]);
            a[4] = fmaf(wv, g1.x, a[4]);
            a[5] = fmaf(wv, g1.y, a[5]);
            a[6] = fmaf(wv, g1.z, a[6]);
            a[7] = fmaf(wv, g1.w, a[7]);
        }
        __syncthreads();
    }

    float* dst = &out[((size_t)b * DQ_ + q) * HW_ + (size_t)hwt * BN3 + hw0];
    f4 o0 = {a[0], a[1], a[2], a[3]};
    f4 o1 = {a[4], a[5], a[6], a[7]};
    *(f4*)dst = o0;
    *(f4*)(dst + 4) = o1;
}

// ============================================================
extern "C" void kernel_launch(void* const* d_in, const int* in_sizes, int n_in,
                              void* d_out, int out_size, void* d_ws, size_t ws_size,
                              hipStream_t stream)
{
    const float* Fp = (const float*)d_in[0];
    const float* Qp = (const float*)d_in[1];
    const float* Wp = (const float*)d_in[2];
    float* out = (float*)d_out;

    const size_t FT_ELEMS = (size_t)B_ * HW_ * C_;     // 25165824
    const size_t W_ELEMS  = (size_t)M_ * C_;           // 786432
    const size_t PART_OFF = 4 * FT_ELEMS + 4 * W_ELEMS; // bytes: 103809024
    const size_t CODE_WS  = PART_OFF + (size_t)B_ * K_ * NHWT * 4;
    const size_t NEED     = CODE_WS + 128;

    if (ws_size >= NEED) {
        ushort_t* FhiT = (ushort_t*)d_ws;
        ushort_t* FloT = FhiT + FT_ELEMS;
        ushort_t* Whi  = FloT + FT_ELEMS;
        ushort_t* Wlo  = Whi + W_ELEMS;
        float* partial = (float*)((char*)d_ws + PART_OFF);
        int* codes_ws  = (int*)((char*)d_ws + CODE_WS);

        k0_splitF<<<dim3(16, 12, B_), 256, 0, stream>>>(Fp, FhiT, FloT);
        k0_splitW<<<dim3(W_ELEMS / 1024), 256, 0, stream>>>(Wp, Whi, Wlo);
        k1_mfma<<<dim3(8, 8, B_), 256, 0, stream>>>(Whi, Wlo, FhiT, FloT, Qp, partial);
        k2_select<<<1, 1024, 0, stream>>>(partial, out, codes_ws);
        k3_sel<<<dim3(B_ * 8), 256, 0, stream>>>(Fp, Wp, codes_ws, out);
    } else {
        float* partial = (float*)d_ws;
        int* codes_ws  = (int*)((char*)d_ws + (size_t)B_ * K_ * NHWT * 4);
        k1_dist_fp32<<<dim3(NMT, NHWT, B_), 256, 0, stream>>>(Fp, Qp, Wp, partial);
        k2_select<<<1, 1024, 0, stream>>>(partial, out, codes_ws);
        k3_sel<<<dim3(B_ * 8), 256, 0, stream>>>(Fp, Wp, codes_ws, out);
    }
}

// Round 3
// 349.897 us; speedup vs baseline: 2.2133x; 1.0810x over previous
//
#include <hip/hip_runtime.h>
#include <cstdint>
#include <cstddef>

typedef float f4 __attribute__((ext_vector_type(4)));
typedef float f32x4 __attribute__((ext_vector_type(4)));
typedef short short8 __attribute__((ext_vector_type(8)));
typedef unsigned short u16x8 __attribute__((ext_vector_type(8)));
typedef unsigned short u16x4 __attribute__((ext_vector_type(4)));
typedef unsigned short ushort_t;

#define B_   32
#define C_   768
#define HW_  1024
#define DQ_  16
#define K_   64
#define M_   1024
#define NHWT 16

#define CODE_OFF 524288
#define LOSS_OFF 524320

// ---------------- bf16 split helpers (RNE) ----------------
__device__ __forceinline__ unsigned bf16_rne_bits(float x) {
    unsigned u = __builtin_bit_cast(unsigned, x);
    return (u + 0x7FFFu + ((u >> 16) & 1u)) >> 16;
}
__device__ __forceinline__ float bits_to_f32(unsigned hi16) {
    unsigned u = hi16 << 16;
    return __builtin_bit_cast(float, u);
}
__device__ __forceinline__ void split_bf16(float x, unsigned short& hi, unsigned short& lo) {
    unsigned h = bf16_rne_bits(x);
    hi = (unsigned short)h;
    float r = x - bits_to_f32(h);
    lo = (unsigned short)bf16_rne_bits(r);
}

// ============================================================
// K0a: split + transpose features: F[b][c][hw] -> FhiT/FloT [b][hw][c]
// ============================================================
__global__ __launch_bounds__(256)
void k0_splitF(const float* __restrict__ Fp,
               ushort_t* __restrict__ FhiT, ushort_t* __restrict__ FloT)
{
    __shared__ float tile[64][65];
    const int t = threadIdx.x;
    const int ht = blockIdx.x, ct = blockIdx.y, b = blockIdx.z;

#pragma unroll
    for (int rep = 0; rep < 4; ++rep) {
        int idx = rep * 256 + t;
        int c_l = idx >> 4;
        int hwf = (idx & 15) * 4;
        f4 v = *(const f4*)&Fp[((size_t)b * C_ + ct * 64 + c_l) * HW_ + ht * 64 + hwf];
        tile[c_l][hwf + 0] = v.x;
        tile[c_l][hwf + 1] = v.y;
        tile[c_l][hwf + 2] = v.z;
        tile[c_l][hwf + 3] = v.w;
    }
    __syncthreads();

#pragma unroll
    for (int rep = 0; rep < 2; ++rep) {
        int hw_l = (t >> 3) + rep * 32;
        int cg   = (t & 7) * 8;
        unsigned short hi[8], lo[8];
#pragma unroll
        for (int j = 0; j < 8; ++j)
            split_bf16(tile[cg + j][hw_l], hi[j], lo[j]);
        size_t o = ((size_t)b * HW_ + ht * 64 + hw_l) * C_ + ct * 64 + cg;
        *(u16x8*)&FhiT[o] = *(u16x8*)hi;
        *(u16x8*)&FloT[o] = *(u16x8*)lo;
    }
}

// ============================================================
// K0b: split W -> Whi/Wlo bf16
// ============================================================
__global__ __launch_bounds__(256)
void k0_splitW(const float* __restrict__ Wp,
               ushort_t* __restrict__ Whi, ushort_t* __restrict__ Wlo)
{
    size_t base = ((size_t)blockIdx.x * 256 + threadIdx.x) * 4;
    f4 v = *(const f4*)&Wp[base];
    unsigned short hi[4], lo[4];
    split_bf16(v.x, hi[0], lo[0]);
    split_bf16(v.y, hi[1], lo[1]);
    split_bf16(v.z, hi[2], lo[2]);
    split_bf16(v.w, hi[3], lo[3]);
    *(u16x4*)&Whi[base] = *(u16x4*)hi;
    *(u16x4*)&Wlo[base] = *(u16x4*)lo;
}

// ============================================================
// K1: 256x256 8-phase MFMA GEMM over concatenated K=2304
//     (Wh*Fh + Wl*Fh + Wh*Fl) + fused distance epilogue.
// grid: 512 blocks x 512 threads (8 waves, 2Mx4N). LDS 128KB dbuf.
// LDS swizzle: 16B-slot s of row r holds global slot s^(r&7);
// staged via inverse-swizzled global source (linear LDS dest).
// ============================================================
#define NKT 36   // 2304/64

__global__ __launch_bounds__(512, 2)
void k1_mfma8(const ushort_t* __restrict__ Whi, const ushort_t* __restrict__ Wlo,
              const ushort_t* __restrict__ FhiT, const ushort_t* __restrict__ FloT,
              const float* __restrict__ Qp, float* __restrict__ partial)
{
    __shared__ ushort_t lds[2][32768];   // per buf: A rows 0..255 @0, B rows @16384 (ushort units)

    const int tid  = threadIdx.x;
    const int w    = tid >> 6;
    const int lane = tid & 63;

    // bijective XCD-chunked swizzle (512 % 8 == 0), mt fastest for F-panel reuse
    const int bid = blockIdx.x;
    const int idx = (bid & 7) * 64 + (bid >> 3);
    const int mt  = idx & 3;
    const int hwt = (idx >> 2) & 3;
    const int b   = idx >> 4;

    const int wm = w >> 2, wn = w & 3;

    // staging role: waves 0-3 stage A (64 rows each), 4-7 stage B
    const bool isA    = (w < 4);
    const int  wrow0  = (w & 3) * 64;
    const int  srow   = lane >> 3;            // 0..7 row within 8-row group
    const int  sslot  = (lane & 7) ^ srow;    // inverse-swizzled source 16B slot
    const int  regoff = isA ? 0 : 16384;
    const size_t abase = (size_t)(mt * 256) * C_;
    const size_t bbase = ((size_t)b * HW_ + hwt * 256) * C_;

    // fragment ds_read offsets (swizzled), ushort units
    const int c15 = lane & 15, d0 = lane >> 4;
    int offA[8][2], offB[4][2];
#pragma unroll
    for (int i = 0; i < 8; ++i) {
        int m = wm * 128 + i * 16 + c15;
#pragma unroll
        for (int kh = 0; kh < 2; ++kh) {
            int d = kh * 4 + d0;
            offA[i][kh] = m * 64 + ((d ^ (m & 7)) << 3);
        }
    }
#pragma unroll
    for (int j = 0; j < 4; ++j) {
        int n = wn * 64 + j * 16 + c15;
#pragma unroll
        for (int kh = 0; kh < 2; ++kh) {
            int d = kh * 4 + d0;
            offB[j][kh] = 16384 + n * 64 + ((d ^ (n & 7)) << 3);
        }
    }

    f32x4 acc[8][4] = {};

    // ---- prologue: stage K-tile 0 (term 0: Whi / FhiT) into buf 0 ----
    {
        const ushort_t* sb = isA ? (Whi + abase) : (FhiT + bbase);
#pragma unroll
        for (int ii = 0; ii < 8; ++ii) {
            const ushort_t* g = sb + (size_t)(wrow0 + ii * 8 + srow) * C_ + sslot * 8;
            __builtin_amdgcn_global_load_lds(
                (const __attribute__((address_space(1))) void*)g,
                (__attribute__((address_space(3))) void*)&lds[0][regoff + (wrow0 + ii * 8) * 64],
                16, 0, 0);
        }
    }
    asm volatile("s_waitcnt vmcnt(0)" ::: "memory");
    __builtin_amdgcn_s_barrier();

    short8 af[4][2], bf0[2][2], bf1[2][2];

#define STAGE2(II)                                                                              \
    if (do_stage) {                                                                             \
        const ushort_t* g0 = sb + (size_t)(wrow0 + (II) * 8 + srow) * C_ + sslot * 8;           \
        __builtin_amdgcn_global_load_lds(                                                       \
            (const __attribute__((address_space(1))) void*)g0,                                  \
            (__attribute__((address_space(3))) void*)(Lnext + regoff + (wrow0 + (II) * 8) * 64),\
            16, 0, 0);                                                                          \
        const ushort_t* g1 = sb + (size_t)(wrow0 + (II) * 8 + 8 + srow) * C_ + sslot * 8;       \
        __builtin_amdgcn_global_load_lds(                                                       \
            (const __attribute__((address_space(1))) void*)g1,                                  \
            (__attribute__((address_space(3))) void*)(Lnext + regoff + (wrow0 + (II) * 8 + 8) * 64),\
            16, 0, 0);                                                                          \
    }

#define QUAD(I0, J0, BF)                                                                        \
    _Pragma("unroll")                                                                           \
    for (int i4 = 0; i4 < 4; ++i4)                                                              \
        _Pragma("unroll")                                                                       \
        for (int j2 = 0; j2 < 2; ++j2)                                                          \
            _Pragma("unroll")                                                                   \
            for (int kh = 0; kh < 2; ++kh)                                                      \
                acc[(I0) + i4][(J0) + j2] = __builtin_amdgcn_mfma_f32_16x16x32_bf16(            \
                    af[i4][kh], BF[j2][kh], acc[(I0) + i4][(J0) + j2], 0, 0, 0);

#define PRE_MFMA()                                          \
    __builtin_amdgcn_s_barrier();                           \
    asm volatile("s_waitcnt lgkmcnt(0)" ::: "memory");      \
    __builtin_amdgcn_sched_barrier(0);                      \
    __builtin_amdgcn_s_setprio(1);

#define POST_MFMA()                                         \
    __builtin_amdgcn_s_setprio(0);                          \
    __builtin_amdgcn_sched_barrier(0);                      \
    __builtin_amdgcn_s_barrier();

    for (int t = 0; t < NKT; ++t) {
        const int cur = t & 1;
        const ushort_t* L = &lds[cur][0];
        ushort_t* Lnext = &lds[cur ^ 1][0];

        const bool do_stage = (t + 1 < NKT);
        const int tt = do_stage ? (t + 1) : 0;
        const int term = (tt >= 24) ? 2 : ((tt >= 12) ? 1 : 0);
        const int c0 = (tt - term * 12) * 64;
        const ushort_t* sb;
        if (isA) sb = ((term == 1) ? Wlo : Whi) + abase + c0;
        else     sb = ((term == 2) ? FloT : FhiT) + bbase + c0;

        // ---------- phase 0: A-quad0 + B-pair0 reads; MFMA quad(0,0) ----------
#pragma unroll
        for (int i4 = 0; i4 < 4; ++i4)
#pragma unroll
            for (int kh = 0; kh < 2; ++kh)
                af[i4][kh] = *(const short8*)&L[offA[i4][kh]];
#pragma unroll
        for (int j2 = 0; j2 < 2; ++j2)
#pragma unroll
            for (int kh = 0; kh < 2; ++kh)
                bf0[j2][kh] = *(const short8*)&L[offB[j2][kh]];
        STAGE2(0)
        PRE_MFMA()
        QUAD(0, 0, bf0)
        POST_MFMA()

        // ---------- phase 1: B-pair1 reads; MFMA quad(0,2) ----------
#pragma unroll
        for (int j2 = 0; j2 < 2; ++j2)
#pragma unroll
            for (int kh = 0; kh < 2; ++kh)
                bf1[j2][kh] = *(const short8*)&L[offB[2 + j2][kh]];
        STAGE2(2)
        PRE_MFMA()
        QUAD(0, 2, bf1)
        POST_MFMA()

        // ---------- phase 2: A-quad1 reads; MFMA quad(4,2) ----------
#pragma unroll
        for (int i4 = 0; i4 < 4; ++i4)
#pragma unroll
            for (int kh = 0; kh < 2; ++kh)
                af[i4][kh] = *(const short8*)&L[offA[4 + i4][kh]];
        STAGE2(4)
        PRE_MFMA()
        QUAD(4, 2, bf1)
        POST_MFMA()

        // ---------- phase 3: no reads; MFMA quad(4,0); tile boundary ----------
        STAGE2(6)
        __builtin_amdgcn_s_barrier();
        __builtin_amdgcn_sched_barrier(0);
        __builtin_amdgcn_s_setprio(1);
        QUAD(4, 0, bf0)
        __builtin_amdgcn_s_setprio(0);
        __builtin_amdgcn_sched_barrier(0);
        asm volatile("s_waitcnt vmcnt(0)" ::: "memory");   // drains only tile t+1's loads
        __builtin_amdgcn_s_barrier();
    }
#undef STAGE2
#undef QUAD
#undef PRE_MFMA
#undef POST_MFMA

    // ---- epilogue: (Q - kv)^2, per-k wave reduction ----
    float qv[4][4];
#pragma unroll
    for (int j = 0; j < 4; ++j) {
        const int hw = hwt * 256 + wn * 64 + j * 16 + c15;
#pragma unroll
        for (int r = 0; r < 4; ++r)
            qv[j][r] = Qp[(size_t)(b * DQ_ + d0 * 4 + r) * HW_ + hw];
    }
#pragma unroll
    for (int i = 0; i < 8; ++i) {
        float s = 0.f;
#pragma unroll
        for (int j = 0; j < 4; ++j)
#pragma unroll
            for (int r = 0; r < 4; ++r) {
                float d = qv[j][r] - acc[i][j][r];
                s = fmaf(d, d, s);
            }
#pragma unroll
        for (int off = 32; off; off >>= 1) s += __shfl_xor(s, off);
        if (lane == 0) {
            const int k = mt * 16 + wm * 8 + i;
            partial[((size_t)b * K_ + k) * NHWT + hwt * 4 + wn] = s;
        }
    }
}

// ============================================================
// K1 fallback (fp32 VALU) if ws too small
// ============================================================
#define BM   256
#define BN   64
#define BC   32
#define NMT  4

__global__ __launch_bounds__(256)
void k1_dist_fp32(const float* __restrict__ Fp, const float* __restrict__ Qp,
                  const float* __restrict__ Wp, float* __restrict__ partial)
{
    __shared__ float w_lds[BC][BM];
    __shared__ float f_lds[BC][BN + 8];
    __shared__ float red[32][8];

    const int tid = threadIdx.x;
    const int mt = blockIdx.x, hwt = blockIdx.y, b = blockIdx.z;
    const int ty = tid >> 3, tx = tid & 7;
    const int m0 = ty * 8, hw0 = tx * 8;

    float acc[8][8];
#pragma unroll
    for (int i = 0; i < 8; ++i)
#pragma unroll
        for (int j = 0; j < 8; ++j) acc[i][j] = 0.f;

    for (int c0 = 0; c0 < C_; c0 += BC) {
#pragma unroll
        for (int i = 0; i < 8; ++i) {
            const int m_l = i * 32 + ty;
            const int c_l = tx * 4;
            const int col = m_l ^ (tx * 4);
            f4 w4 = *(const f4*)&Wp[(size_t)(mt * BM + m_l) * C_ + c0 + c_l];
            w_lds[c_l + 0][col] = w4.x;
            w_lds[c_l + 1][col] = w4.y;
            w_lds[c_l + 2][col] = w4.z;
            w_lds[c_l + 3][col] = w4.w;
        }
        {
            const int c = tid >> 3;
            const int hw = (tid & 7) * 8;
            const float* src = &Fp[((size_t)b * C_ + c0 + c) * HW_ + (size_t)hwt * BN + hw];
            *(f4*)&f_lds[c][hw]     = *(const f4*)src;
            *(f4*)&f_lds[c][hw + 4] = *(const f4*)(src + 4);
        }
        __syncthreads();

#pragma unroll 4
        for (int cc = 0; cc < BC; ++cc) {
            const int sw = ((cc >> 2) & 7) * 4;
            const int colA = m0 ^ sw;
            f4 w0 = *(const f4*)&w_lds[cc][colA];
            f4 w1 = *(const f4*)&w_lds[cc][colA ^ 4];
            f4 g0 = *(const f4*)&f_lds[cc][hw0];
            f4 g1 = *(const f4*)&f_lds[cc][hw0 + 4];
            const float wa[8] = {w0.x, w0.y, w0.z, w0.w, w1.x, w1.y, w1.z, w1.w};
            const float fv[8] = {g0.x, g0.y, g0.z, g0.w, g1.x, g1.y, g1.z, g1.w};
#pragma unroll
            for (int i = 0; i < 8; ++i)
#pragma unroll
                for (int j = 0; j < 8; ++j)
                    acc[i][j] = fmaf(wa[i], fv[j], acc[i][j]);
        }
        __syncthreads();
    }

    const int q0 = (ty & 1) * 8;
    float s = 0.f;
#pragma unroll
    for (int i = 0; i < 8; ++i) {
        const float* qp = &Qp[((size_t)b * DQ_ + q0 + i) * HW_ + (size_t)hwt * BN + hw0];
        f4 qa = *(const f4*)qp;
        f4 qb = *(const f4*)(qp + 4);
        float d;
        d = qa.x - acc[i][0]; s = fmaf(d, d, s);
        d = qa.y - acc[i][1]; s = fmaf(d, d, s);
        d = qa.z - acc[i][2]; s = fmaf(d, d, s);
        d = qa.w - acc[i][3]; s = fmaf(d, d, s);
        d = qb.x - acc[i][4]; s = fmaf(d, d, s);
        d = qb.y - acc[i][5]; s = fmaf(d, d, s);
        d = qb.z - acc[i][6]; s = fmaf(d, d, s);
        d = qb.w - acc[i][7]; s = fmaf(d, d, s);
    }
    red[ty][tx] = s;
    __syncthreads();
    if (tid < 16) {
        float t = 0.f;
#pragma unroll
        for (int r = 0; r < 2; ++r)
#pragma unroll
            for (int x = 0; x < 8; ++x) t += red[tid * 2 + r][x];
        partial[((size_t)b * K_ + mt * 16 + tid) * NHWT + hwt] = t;
    }
}

// ============================================================
// K2: reduce partials -> argmin + loss
// ============================================================
__global__ __launch_bounds__(1024)
void k2_select(const float* __restrict__ partial, float* __restrict__ out,
               int* __restrict__ codes_ws)
{
    const int tid = threadIdx.x;
    const int b = tid >> 5, kk = tid & 31;
    float s0 = 0.f, s1 = 0.f;
#pragma unroll
    for (int h = 0; h < NHWT; ++h) {
        s0 += partial[((size_t)b * K_ + kk) * NHWT + h];
        s1 += partial[((size_t)b * K_ + kk + 32) * NHWT + h];
    }
    float bv = s0; int bk = kk;
    if (s1 < bv) { bv = s1; bk = kk + 32; }
#pragma unroll
    for (int m = 16; m >= 1; m >>= 1) {
        float ov = __shfl_xor(bv, m);
        int   ok = __shfl_xor(bk, m);
        if (ov < bv || (ov == bv && ok < bk)) { bv = ov; bk = ok; }
    }
    __shared__ float mins[32];
    if (kk == 0) {
        out[CODE_OFF + b] = (float)bk;
        codes_ws[b] = bk;
        mins[b] = bv;
    }
    __syncthreads();
    if (tid == 0) {
        float t = 0.f;
#pragma unroll
        for (int i = 0; i < 32; ++i) t += mins[i];
        out[LOSS_OFF] = t * (1.0f / 524288.0f);
    }
}

// ============================================================
// K3: exact fp32 recompute of sel for the chosen code
// ============================================================
#define BN3 128
#define BC3 32

__global__ __launch_bounds__(256)
void k3_sel(const float* __restrict__ Fp, const float* __restrict__ Wp,
            const int* __restrict__ codes_ws, float* __restrict__ out)
{
    __shared__ float f_lds[BC3][BN3];
    __shared__ float w_lds[DQ_][33];

    const int tid = threadIdx.x;
    const int b = blockIdx.x >> 3, hwt = blockIdx.x & 7;
    const int code = codes_ws[b];
    const int q = tid >> 4;
    const int hw0 = (tid & 15) * 8;

    float a[8] = {0.f, 0.f, 0.f, 0.f, 0.f, 0.f, 0.f, 0.f};

    for (int c0 = 0; c0 < C_; c0 += BC3) {
        if (tid < 128) {
            const int qq = tid >> 3, c4 = (tid & 7) * 4;
            f4 w4 = *(const f4*)&Wp[((size_t)code * DQ_ + qq) * C_ + c0 + c4];
            w_lds[qq][c4 + 0] = w4.x;
            w_lds[qq][c4 + 1] = w4.y;
            w_lds[qq][c4 + 2] = w4.z;
            w_lds[qq][c4 + 3] = w4.w;
        }
        {
            const int c = tid >> 3;
            const int hw = (tid & 7) * 16;
            const float* src = &Fp[((size_t)b * C_ + c0 + c) * HW_ + (size_t)hwt * BN3 + hw];
            *(f4*)&f_lds[c][hw]      = *(const f4*)(src);
            *(f4*)&f_lds[c][hw + 4]  = *(const f4*)(src + 4);
            *(f4*)&f_lds[c][hw + 8]  = *(const f4*)(src + 8);
            *(f4*)&f_lds[c][hw + 12] = *(const f4*)(src + 12);
        }
        __syncthreads();
#pragma unroll 4
        for (int cc = 0; cc < BC3; ++cc) {
            const float wv = w_lds[q][cc];
            f4 g0 = *(const f4*)&f_lds[cc][hw0];
            f4 g1 = *(const f4*)&f_lds[cc][hw0 + 4];
            a[0] = fmaf(wv, g0.x, a[0]);
            a[1] = fmaf(wv, g0.y, a[1]);
            a[2] = fmaf(wv, g0.z, a[2]);
            a[3] = fmaf(wv, g0.w, a[3]);
            a[4] = fmaf(wv, g1.x, a[4]);
            a[5] = fmaf(wv, g1.y, a[5]);
            a[6] = fmaf(wv, g1.z, a[6]);
            a[7] = fmaf(wv, g1.w, a[7]);
        }
        __syncthreads();
    }

    float* dst = &out[((size_t)b * DQ_ + q) * HW_ + (size_t)hwt * BN3 + hw0];
    f4 o0 = {a[0], a[1], a[2], a[3]};
    f4 o1 = {a[4], a[5], a[6], a[7]};
    *(f4*)dst = o0;
    *(f4*)(dst + 4) = o1;
}

// ============================================================
extern "C" void kernel_launch(void* const* d_in, const int* in_sizes, int n_in,
                              void* d_out, int out_size, void* d_ws, size_t ws_size,
                              hipStream_t stream)
{
    const float* Fp = (const float*)d_in[0];
    const float* Qp = (const float*)d_in[1];
    const float* Wp = (const float*)d_in[2];
    float* out = (float*)d_out;

    const size_t FT_ELEMS = (size_t)B_ * HW_ * C_;
    const size_t W_ELEMS  = (size_t)M_ * C_;
    const size_t PART_OFF = 4 * FT_ELEMS + 4 * W_ELEMS;
    const size_t CODE_WS  = PART_OFF + (size_t)B_ * K_ * NHWT * 4;
    const size_t NEED     = CODE_WS + 128;

    if (ws_size >= NEED) {
        ushort_t* FhiT = (ushort_t*)d_ws;
        ushort_t* FloT = FhiT + FT_ELEMS;
        ushort_t* Whi  = FloT + FT_ELEMS;
        ushort_t* Wlo  = Whi + W_ELEMS;
        float* partial = (float*)((char*)d_ws + PART_OFF);
        int* codes_ws  = (int*)((char*)d_ws + CODE_WS);

        k0_splitF<<<dim3(16, 12, B_), 256, 0, stream>>>(Fp, FhiT, FloT);
        k0_splitW<<<dim3(W_ELEMS / 1024), 256, 0, stream>>>(Wp, Whi, Wlo);
        k1_mfma8<<<dim3(512), 512, 0, stream>>>(Whi, Wlo, FhiT, FloT, Qp, partial);
        k2_select<<<1, 1024, 0, stream>>>(partial, out, codes_ws);
        k3_sel<<<dim3(B_ * 8), 256, 0, stream>>>(Fp, Wp, codes_ws, out);
    } else {
        float* partial = (float*)d_ws;
        int* codes_ws  = (int*)((char*)d_ws + (size_t)B_ * K_ * NHWT * 4);
        k1_dist_fp32<<<dim3(NMT, NHWT, B_), 256, 0, stream>>>(Fp, Qp, Wp, partial);
        k2_select<<<1, 1024, 0, stream>>>(partial, out, codes_ws);
        k3_sel<<<dim3(B_ * 8), 256, 0, stream>>>(Fp, Wp, codes_ws, out);
    }
}

// Round 4
// 309.580 us; speedup vs baseline: 2.5016x; 1.1302x over previous
//
#include <hip/hip_runtime.h>
#include <cstdint>
#include <cstddef>

typedef float f4 __attribute__((ext_vector_type(4)));
typedef float f32x4 __attribute__((ext_vector_type(4)));
typedef short short8 __attribute__((ext_vector_type(8)));
typedef unsigned short u16x8 __attribute__((ext_vector_type(8)));
typedef unsigned short u16x4 __attribute__((ext_vector_type(4)));
typedef unsigned short ushort_t;

#define B_   32
#define C_   768
#define HW_  1024
#define DQ_  16
#define K_   64
#define M_   1024
#define NHWT 16
#define NCT  12     // C_/64

#define CODE_OFF 524288
#define LOSS_OFF 524320

// ---------------- bf16 split helpers (RNE) ----------------
__device__ __forceinline__ unsigned bf16_rne_bits(float x) {
    unsigned u = __builtin_bit_cast(unsigned, x);
    return (u + 0x7FFFu + ((u >> 16) & 1u)) >> 16;
}
__device__ __forceinline__ float bits_to_f32(unsigned hi16) {
    unsigned u = hi16 << 16;
    return __builtin_bit_cast(float, u);
}
__device__ __forceinline__ void split_bf16(float x, unsigned short& hi, unsigned short& lo) {
    unsigned h = bf16_rne_bits(x);
    hi = (unsigned short)h;
    float r = x - bits_to_f32(h);
    lo = (unsigned short)bf16_rne_bits(r);
}

// ============================================================
// Split-tensor layout (K-tiled, contiguous K-tiles of 64 c):
//   Whi/Wlo :  [ct(12)][m(1024)][cl(64)]
//   FhiT/FloT: [b(32)][ct(12)][hw(1024)][cl(64)]
// Row stride = 128 B -> every staging read / k0 write is contiguous.
// ============================================================

// ============================================================
// K0a: split + transpose features F[b][c][hw] -> tiled layout
// ============================================================
__global__ __launch_bounds__(256)
void k0_splitF(const float* __restrict__ Fp,
               ushort_t* __restrict__ FhiT, ushort_t* __restrict__ FloT)
{
    __shared__ float tile[64][65];
    const int t = threadIdx.x;
    const int ht = blockIdx.x, ct = blockIdx.y, b = blockIdx.z;

#pragma unroll
    for (int rep = 0; rep < 4; ++rep) {
        int idx = rep * 256 + t;
        int c_l = idx >> 4;
        int hwf = (idx & 15) * 4;
        f4 v = *(const f4*)&Fp[((size_t)b * C_ + ct * 64 + c_l) * HW_ + ht * 64 + hwf];
        tile[c_l][hwf + 0] = v.x;
        tile[c_l][hwf + 1] = v.y;
        tile[c_l][hwf + 2] = v.z;
        tile[c_l][hwf + 3] = v.w;
    }
    __syncthreads();

#pragma unroll
    for (int rep = 0; rep < 2; ++rep) {
        int hw_l = (t >> 3) + rep * 32;
        int cg   = (t & 7) * 8;
        unsigned short hi[8], lo[8];
#pragma unroll
        for (int j = 0; j < 8; ++j)
            split_bf16(tile[cg + j][hw_l], hi[j], lo[j]);
        size_t o = (((size_t)(b * NCT + ct)) * HW_ + ht * 64 + hw_l) * 64 + cg;
        *(u16x8*)&FhiT[o] = *(u16x8*)hi;
        *(u16x8*)&FloT[o] = *(u16x8*)lo;
    }
}

// ============================================================
// K0b: split W[m(1024)][c(768)] -> tiled layout [ct][m][64]
// ============================================================
__global__ __launch_bounds__(256)
void k0_splitW(const float* __restrict__ Wp,
               ushort_t* __restrict__ Whi, ushort_t* __restrict__ Wlo)
{
    const unsigned gid = blockIdx.x * 256 + threadIdx.x;
    const unsigned base = gid * 4;                 // flat [m][c]
    const unsigned m = base / C_;
    const unsigned c = base - m * C_;
    const unsigned ct = c >> 6, cl = c & 63;
    f4 v = *(const f4*)&Wp[base];
    unsigned short hi[4], lo[4];
    split_bf16(v.x, hi[0], lo[0]);
    split_bf16(v.y, hi[1], lo[1]);
    split_bf16(v.z, hi[2], lo[2]);
    split_bf16(v.w, hi[3], lo[3]);
    size_t o = ((size_t)ct * M_ + m) * 64 + cl;
    *(u16x4*)&Whi[o] = *(u16x4*)hi;
    *(u16x4*)&Wlo[o] = *(u16x4*)lo;
}

// ============================================================
// K1: 256x256 8-phase MFMA GEMM over concatenated K=2304
//     (Wh*Fh + Wl*Fh + Wh*Fl) + fused distance epilogue.
// All staging issued in phases 0-1; vmcnt(0) at tile end is >=2
// MFMA phases after the last issue.
// ============================================================
#define NKT 36   // 3 terms x 12 K-tiles

__global__ __launch_bounds__(512, 2)
void k1_mfma8(const ushort_t* __restrict__ Whi, const ushort_t* __restrict__ Wlo,
              const ushort_t* __restrict__ FhiT, const ushort_t* __restrict__ FloT,
              const float* __restrict__ Qp, float* __restrict__ partial)
{
    __shared__ ushort_t lds[2][32768];   // per buf: A rows @0, B rows @16384

    const int tid  = threadIdx.x;
    const int w    = tid >> 6;
    const int lane = tid & 63;

    const int bid = blockIdx.x;
    const int idx = (bid & 7) * 64 + (bid >> 3);   // bijective XCD swizzle
    const int mt  = idx & 3;
    const int hwt = (idx >> 2) & 3;
    const int b   = idx >> 4;

    const int wm = w >> 2, wn = w & 3;

    const bool isA    = (w < 4);
    const int  wrow0  = (w & 3) * 64;
    const int  srow   = lane >> 3;
    const int  sslot  = (lane & 7) ^ srow;
    const int  regoff = isA ? 0 : 16384;

    const int c15 = lane & 15, d0 = lane >> 4;
    int offA[8][2], offB[4][2];
#pragma unroll
    for (int i = 0; i < 8; ++i) {
        int m = wm * 128 + i * 16 + c15;
#pragma unroll
        for (int kh = 0; kh < 2; ++kh) {
            int d = kh * 4 + d0;
            offA[i][kh] = m * 64 + ((d ^ (m & 7)) << 3);
        }
    }
#pragma unroll
    for (int j = 0; j < 4; ++j) {
        int n = wn * 64 + j * 16 + c15;
#pragma unroll
        for (int kh = 0; kh < 2; ++kh) {
            int d = kh * 4 + d0;
            offB[j][kh] = 16384 + n * 64 + ((d ^ (n & 7)) << 3);
        }
    }

    f32x4 acc[8][4] = {};

    // ---- prologue: stage K-tile 0 (Whi / FhiT, ct=0) into buf 0 ----
    {
        const ushort_t* sb = isA ? (Whi + (size_t)(mt * 256) * 64)
                                 : (FhiT + ((size_t)(b * NCT) * HW_ + hwt * 256) * 64);
#pragma unroll
        for (int ii = 0; ii < 8; ++ii) {
            const ushort_t* g = sb + (size_t)(wrow0 + ii * 8 + srow) * 64 + sslot * 8;
            __builtin_amdgcn_global_load_lds(
                (const __attribute__((address_space(1))) void*)g,
                (__attribute__((address_space(3))) void*)&lds[0][regoff + (wrow0 + ii * 8) * 64],
                16, 0, 0);
        }
    }
    asm volatile("s_waitcnt vmcnt(0)" ::: "memory");
    __builtin_amdgcn_s_barrier();

    short8 af[4][2], bf0[2][2], bf1[2][2];

#define STAGE4(II)                                                                               \
    if (do_stage) {                                                                              \
        _Pragma("unroll")                                                                        \
        for (int ii = (II); ii < (II) + 4; ++ii) {                                               \
            const ushort_t* g = sb + (size_t)(wrow0 + ii * 8 + srow) * 64 + sslot * 8;           \
            __builtin_amdgcn_global_load_lds(                                                    \
                (const __attribute__((address_space(1))) void*)g,                                \
                (__attribute__((address_space(3))) void*)(Lnext + regoff + (wrow0 + ii * 8) * 64),\
                16, 0, 0);                                                                       \
        }                                                                                        \
    }

#define QUAD(I0, J0, BF)                                                                         \
    _Pragma("unroll")                                                                            \
    for (int i4 = 0; i4 < 4; ++i4)                                                               \
        _Pragma("unroll")                                                                        \
        for (int j2 = 0; j2 < 2; ++j2)                                                           \
            _Pragma("unroll")                                                                    \
            for (int kh = 0; kh < 2; ++kh)                                                       \
                acc[(I0) + i4][(J0) + j2] = __builtin_amdgcn_mfma_f32_16x16x32_bf16(             \
                    af[i4][kh], BF[j2][kh], acc[(I0) + i4][(J0) + j2], 0, 0, 0);

#define PRE_MFMA()                                          \
    __builtin_amdgcn_s_barrier();                           \
    asm volatile("s_waitcnt lgkmcnt(0)" ::: "memory");      \
    __builtin_amdgcn_sched_barrier(0);                      \
    __builtin_amdgcn_s_setprio(1);

#define POST_MFMA()                                         \
    __builtin_amdgcn_s_setprio(0);                          \
    __builtin_amdgcn_sched_barrier(0);                      \
    __builtin_amdgcn_s_barrier();

    for (int t = 0; t < NKT; ++t) {
        const int cur = t & 1;
        const ushort_t* L = &lds[cur][0];
        ushort_t* Lnext = &lds[cur ^ 1][0];

        const bool do_stage = (t + 1 < NKT);
        const int tt = do_stage ? (t + 1) : 0;
        const int term = (tt >= 24) ? 2 : ((tt >= 12) ? 1 : 0);
        const int ct = tt - term * 12;
        const ushort_t* sb;
        if (isA) sb = ((term == 1) ? Wlo : Whi) + ((size_t)ct * M_ + mt * 256) * 64;
        else     sb = ((term == 2) ? FloT : FhiT) + ((size_t)(b * NCT + ct) * HW_ + hwt * 256) * 64;

        // ---------- phase 0: A0-3 + B0-1 reads; stage rows 0-31; MFMA quad(0,0) ----------
#pragma unroll
        for (int i4 = 0; i4 < 4; ++i4)
#pragma unroll
            for (int kh = 0; kh < 2; ++kh)
                af[i4][kh] = *(const short8*)&L[offA[i4][kh]];
#pragma unroll
        for (int j2 = 0; j2 < 2; ++j2)
#pragma unroll
            for (int kh = 0; kh < 2; ++kh)
                bf0[j2][kh] = *(const short8*)&L[offB[j2][kh]];
        STAGE4(0)
        PRE_MFMA()
        QUAD(0, 0, bf0)
        POST_MFMA()

        // ---------- phase 1: B2-3 reads; stage rows 32-63; MFMA quad(0,2) ----------
#pragma unroll
        for (int j2 = 0; j2 < 2; ++j2)
#pragma unroll
            for (int kh = 0; kh < 2; ++kh)
                bf1[j2][kh] = *(const short8*)&L[offB[2 + j2][kh]];
        STAGE4(4)
        PRE_MFMA()
        QUAD(0, 2, bf1)
        POST_MFMA()

        // ---------- phase 2: A4-7 reads; MFMA quad(4,2) ----------
#pragma unroll
        for (int i4 = 0; i4 < 4; ++i4)
#pragma unroll
            for (int kh = 0; kh < 2; ++kh)
                af[i4][kh] = *(const short8*)&L[offA[4 + i4][kh]];
        PRE_MFMA()
        QUAD(4, 2, bf1)
        POST_MFMA()

        // ---------- phase 3: MFMA quad(4,0); tile boundary ----------
        __builtin_amdgcn_s_barrier();
        __builtin_amdgcn_sched_barrier(0);
        __builtin_amdgcn_s_setprio(1);
        QUAD(4, 0, bf0)
        __builtin_amdgcn_s_setprio(0);
        __builtin_amdgcn_sched_barrier(0);
        asm volatile("s_waitcnt vmcnt(0)" ::: "memory");
        __builtin_amdgcn_s_barrier();
    }
#undef STAGE4
#undef QUAD
#undef PRE_MFMA
#undef POST_MFMA

    // ---- epilogue: (Q - kv)^2, per-k wave reduction ----
    float qv[4][4];
#pragma unroll
    for (int j = 0; j < 4; ++j) {
        const int hw = hwt * 256 + wn * 64 + j * 16 + c15;
#pragma unroll
        for (int r = 0; r < 4; ++r)
            qv[j][r] = Qp[(size_t)(b * DQ_ + d0 * 4 + r) * HW_ + hw];
    }
#pragma unroll
    for (int i = 0; i < 8; ++i) {
        float s = 0.f;
#pragma unroll
        for (int j = 0; j < 4; ++j)
#pragma unroll
            for (int r = 0; r < 4; ++r) {
                float d = qv[j][r] - acc[i][j][r];
                s = fmaf(d, d, s);
            }
#pragma unroll
        for (int off = 32; off; off >>= 1) s += __shfl_xor(s, off);
        if (lane == 0) {
            const int k = mt * 16 + wm * 8 + i;
            partial[((size_t)b * K_ + k) * NHWT + hwt * 4 + wn] = s;
        }
    }
}

// ============================================================
// K2: reduce partials -> argmin + loss
// ============================================================
__global__ __launch_bounds__(1024)
void k2_select(const float* __restrict__ partial, float* __restrict__ out,
               int* __restrict__ codes_ws)
{
    const int tid = threadIdx.x;
    const int b = tid >> 5, kk = tid & 31;
    float s0 = 0.f, s1 = 0.f;
#pragma unroll
    for (int h = 0; h < NHWT; ++h) {
        s0 += partial[((size_t)b * K_ + kk) * NHWT + h];
        s1 += partial[((size_t)b * K_ + kk + 32) * NHWT + h];
    }
    float bv = s0; int bk = kk;
    if (s1 < bv) { bv = s1; bk = kk + 32; }
#pragma unroll
    for (int m = 16; m >= 1; m >>= 1) {
        float ov = __shfl_xor(bv, m);
        int   ok = __shfl_xor(bk, m);
        if (ov < bv || (ov == bv && ok < bk)) { bv = ov; bk = ok; }
    }
    __shared__ float mins[32];
    if (kk == 0) {
        out[CODE_OFF + b] = (float)bk;
        codes_ws[b] = bk;
        mins[b] = bv;
    }
    __syncthreads();
    if (tid == 0) {
        float t = 0.f;
#pragma unroll
        for (int i = 0; i < 32; ++i) t += mins[i];
        out[LOSS_OFF] = t * (1.0f / 524288.0f);
    }
}

// ============================================================
// K3: sel via bf16-triple MFMA from split tensors.
// grid (32 b x 16 hwt of 64), 256 thr = 4 waves. dbuf LDS 40 KB.
// ============================================================
__global__ __launch_bounds__(256)
void k3_mfma(const ushort_t* __restrict__ Whi, const ushort_t* __restrict__ Wlo,
             const ushort_t* __restrict__ FhiT, const ushort_t* __restrict__ FloT,
             const int* __restrict__ codes_ws, float* __restrict__ out)
{
    __shared__ ushort_t lds3[2][10240];  // A:32 rows @0 (hi 0-15, lo 16-31); Bhi @2048; Blo @6144

    const int tid = threadIdx.x;
    const int w = tid >> 6, lane = tid & 63;
    const int b = blockIdx.x >> 4, hwt = blockIdx.x & 15;
    const int code = codes_ws[b];

    const int srow = lane >> 3, sslot = (lane & 7) ^ srow;
    const int c15 = lane & 15, d0 = lane >> 4;

    int offAhi[2], offAlo[2], offBh[2], offBl[2];
#pragma unroll
    for (int kh = 0; kh < 2; ++kh) {
        const int d = kh * 4 + d0;
        const int mA = c15;
        offAhi[kh] = mA * 64 + ((d ^ (mA & 7)) << 3);
        const int mAl = 16 + c15;
        offAlo[kh] = mAl * 64 + ((d ^ (mAl & 7)) << 3);
        const int rB = w * 16 + c15;
        offBh[kh] = 2048 + rB * 64 + ((d ^ (rB & 7)) << 3);
        offBl[kh] = 6144 + rB * 64 + ((d ^ (rB & 7)) << 3);
    }

#define K3_STAGE(CT, BUF)                                                                        \
    {                                                                                            \
        ushort_t* Lb = &lds3[(BUF)][0];                                                          \
        const ushort_t* bhp = FhiT + ((size_t)(b * NCT + (CT)) * HW_ + hwt * 64) * 64;           \
        const ushort_t* blp = FloT + ((size_t)(b * NCT + (CT)) * HW_ + hwt * 64) * 64;           \
        _Pragma("unroll")                                                                        \
        for (int ii = 0; ii < 2; ++ii) {                                                         \
            __builtin_amdgcn_global_load_lds(                                                    \
                (const __attribute__((address_space(1))) void*)(bhp + (w * 16 + ii * 8 + srow) * 64 + sslot * 8), \
                (__attribute__((address_space(3))) void*)(Lb + 2048 + (w * 16 + ii * 8) * 64),   \
                16, 0, 0);                                                                       \
            __builtin_amdgcn_global_load_lds(                                                    \
                (const __attribute__((address_space(1))) void*)(blp + (w * 16 + ii * 8 + srow) * 64 + sslot * 8), \
                (__attribute__((address_space(3))) void*)(Lb + 6144 + (w * 16 + ii * 8) * 64),   \
                16, 0, 0);                                                                       \
        }                                                                                        \
        if (w == 0) {                                                                            \
            const ushort_t* ahp = Whi + ((size_t)(CT) * M_ + code * 16) * 64;                    \
            _Pragma("unroll")                                                                    \
            for (int ii = 0; ii < 2; ++ii)                                                       \
                __builtin_amdgcn_global_load_lds(                                                \
                    (const __attribute__((address_space(1))) void*)(ahp + (ii * 8 + srow) * 64 + sslot * 8), \
                    (__attribute__((address_space(3))) void*)(Lb + (ii * 8) * 64),               \
                    16, 0, 0);                                                                   \
        } else if (w == 1) {                                                                     \
            const ushort_t* alp = Wlo + ((size_t)(CT) * M_ + code * 16) * 64;                    \
            _Pragma("unroll")                                                                    \
            for (int ii = 0; ii < 2; ++ii)                                                       \
                __builtin_amdgcn_global_load_lds(                                                \
                    (const __attribute__((address_space(1))) void*)(alp + (ii * 8 + srow) * 64 + sslot * 8), \
                    (__attribute__((address_space(3))) void*)(Lb + (16 + ii * 8) * 64),          \
                    16, 0, 0);                                                                   \
        }                                                                                        \
    }

    f32x4 acc = {};

    K3_STAGE(0, 0)
    asm volatile("s_waitcnt vmcnt(0)" ::: "memory");
    __syncthreads();

    for (int ct = 0; ct < NCT; ++ct) {
        const int cur = ct & 1;
        if (ct + 1 < NCT) K3_STAGE(ct + 1, cur ^ 1)
        const ushort_t* L = &lds3[cur][0];
        short8 ah[2], al2[2], bh[2], bl[2];
#pragma unroll
        for (int kh = 0; kh < 2; ++kh) {
            ah[kh]  = *(const short8*)&L[offAhi[kh]];
            al2[kh] = *(const short8*)&L[offAlo[kh]];
            bh[kh]  = *(const short8*)&L[offBh[kh]];
            bl[kh]  = *(const short8*)&L[offBl[kh]];
        }
#pragma unroll
        for (int kh = 0; kh < 2; ++kh) {
            acc = __builtin_amdgcn_mfma_f32_16x16x32_bf16(ah[kh], bh[kh], acc, 0, 0, 0);
            acc = __builtin_amdgcn_mfma_f32_16x16x32_bf16(ah[kh], bl[kh], acc, 0, 0, 0);
            acc = __builtin_amdgcn_mfma_f32_16x16x32_bf16(al2[kh], bh[kh], acc, 0, 0, 0);
        }
        asm volatile("s_waitcnt vmcnt(0)" ::: "memory");
        __syncthreads();
    }
#undef K3_STAGE

#pragma unroll
    for (int r = 0; r < 4; ++r) {
        const int q = d0 * 4 + r;
        out[((size_t)(b * DQ_ + q)) * HW_ + hwt * 64 + w * 16 + c15] = acc[r];
    }
}

// ============================================================
// Fallback tier (ws too small): fp32 VALU path, old layouts
// ============================================================
#define BM   256
#define BN   64
#define BC   32
#define NMT  4

__global__ __launch_bounds__(256)
void k1_dist_fp32(const float* __restrict__ Fp, const float* __restrict__ Qp,
                  const float* __restrict__ Wp, float* __restrict__ partial)
{
    __shared__ float w_lds[BC][BM];
    __shared__ float f_lds[BC][BN + 8];
    __shared__ float red[32][8];

    const int tid = threadIdx.x;
    const int mt = blockIdx.x, hwt = blockIdx.y, b = blockIdx.z;
    const int ty = tid >> 3, tx = tid & 7;
    const int m0 = ty * 8, hw0 = tx * 8;

    float acc[8][8];
#pragma unroll
    for (int i = 0; i < 8; ++i)
#pragma unroll
        for (int j = 0; j < 8; ++j) acc[i][j] = 0.f;

    for (int c0 = 0; c0 < C_; c0 += BC) {
#pragma unroll
        for (int i = 0; i < 8; ++i) {
            const int m_l = i * 32 + ty;
            const int c_l = tx * 4;
            const int col = m_l ^ (tx * 4);
            f4 w4 = *(const f4*)&Wp[(size_t)(mt * BM + m_l) * C_ + c0 + c_l];
            w_lds[c_l + 0][col] = w4.x;
            w_lds[c_l + 1][col] = w4.y;
            w_lds[c_l + 2][col] = w4.z;
            w_lds[c_l + 3][col] = w4.w;
        }
        {
            const int c = tid >> 3;
            const int hw = (tid & 7) * 8;
            const float* src = &Fp[((size_t)b * C_ + c0 + c) * HW_ + (size_t)hwt * BN + hw];
            *(f4*)&f_lds[c][hw]     = *(const f4*)src;
            *(f4*)&f_lds[c][hw + 4] = *(const f4*)(src + 4);
        }
        __syncthreads();

#pragma unroll 4
        for (int cc = 0; cc < BC; ++cc) {
            const int sw = ((cc >> 2) & 7) * 4;
            const int colA = m0 ^ sw;
            f4 w0 = *(const f4*)&w_lds[cc][colA];
            f4 w1 = *(const f4*)&w_lds[cc][colA ^ 4];
            f4 g0 = *(const f4*)&f_lds[cc][hw0];
            f4 g1 = *(const f4*)&f_lds[cc][hw0 + 4];
            const float wa[8] = {w0.x, w0.y, w0.z, w0.w, w1.x, w1.y, w1.z, w1.w};
            const float fv[8] = {g0.x, g0.y, g0.z, g0.w, g1.x, g1.y, g1.z, g1.w};
#pragma unroll
            for (int i = 0; i < 8; ++i)
#pragma unroll
                for (int j = 0; j < 8; ++j)
                    acc[i][j] = fmaf(wa[i], fv[j], acc[i][j]);
        }
        __syncthreads();
    }

    const int q0 = (ty & 1) * 8;
    float s = 0.f;
#pragma unroll
    for (int i = 0; i < 8; ++i) {
        const float* qp = &Qp[((size_t)b * DQ_ + q0 + i) * HW_ + (size_t)hwt * BN + hw0];
        f4 qa = *(const f4*)qp;
        f4 qb = *(const f4*)(qp + 4);
        float d;
        d = qa.x - acc[i][0]; s = fmaf(d, d, s);
        d = qa.y - acc[i][1]; s = fmaf(d, d, s);
        d = qa.z - acc[i][2]; s = fmaf(d, d, s);
        d = qa.w - acc[i][3]; s = fmaf(d, d, s);
        d = qb.x - acc[i][4]; s = fmaf(d, d, s);
        d = qb.y - acc[i][5]; s = fmaf(d, d, s);
        d = qb.z - acc[i][6]; s = fmaf(d, d, s);
        d = qb.w - acc[i][7]; s = fmaf(d, d, s);
    }
    red[ty][tx] = s;
    __syncthreads();
    if (tid < 16) {
        float t = 0.f;
#pragma unroll
        for (int r = 0; r < 2; ++r)
#pragma unroll
            for (int x = 0; x < 8; ++x) t += red[tid * 2 + r][x];
        partial[((size_t)b * K_ + mt * 16 + tid) * NHWT + hwt] = t;
    }
}

#define BN3 128
#define BC3 32

__global__ __launch_bounds__(256)
void k3_sel(const float* __restrict__ Fp, const float* __restrict__ Wp,
            const int* __restrict__ codes_ws, float* __restrict__ out)
{
    __shared__ float f_lds[BC3][BN3];
    __shared__ float w_lds[DQ_][33];

    const int tid = threadIdx.x;
    const int b = blockIdx.x >> 3, hwt = blockIdx.x & 7;
    const int code = codes_ws[b];
    const int q = tid >> 4;
    const int hw0 = (tid & 15) * 8;

    float a[8] = {0.f, 0.f, 0.f, 0.f, 0.f, 0.f, 0.f, 0.f};

    for (int c0 = 0; c0 < C_; c0 += BC3) {
        if (tid < 128) {
            const int qq = tid >> 3, c4 = (tid & 7) * 4;
            f4 w4 = *(const f4*)&Wp[((size_t)code * DQ_ + qq) * C_ + c0 + c4];
            w_lds[qq][c4 + 0] = w4.x;
            w_lds[qq][c4 + 1] = w4.y;
            w_lds[qq][c4 + 2] = w4.z;
            w_lds[qq][c4 + 3] = w4.w;
        }
        {
            const int c = tid >> 3;
            const int hw = (tid & 7) * 16;
            const float* src = &Fp[((size_t)b * C_ + c0 + c) * HW_ + (size_t)hwt * BN3 + hw];
            *(f4*)&f_lds[c][hw]      = *(const f4*)(src);
            *(f4*)&f_lds[c][hw + 4]  = *(const f4*)(src + 4);
            *(f4*)&f_lds[c][hw + 8]  = *(const f4*)(src + 8);
            *(f4*)&f_lds[c][hw + 12] = *(const f4*)(src + 12);
        }
        __syncthreads();
#pragma unroll 4
        for (int cc = 0; cc < BC3; ++cc) {
            const float wv = w_lds[q][cc];
            f4 g0 = *(const f4*)&f_lds[cc][hw0];
            f4 g1 = *(const f4*)&f_lds[cc][hw0 + 4];
            a[0] = fmaf(wv, g0.x, a[0]);
            a[1] = fmaf(wv, g0.y, a[1]);
            a[2] = fmaf(wv, g0.z, a[2]);
            a[3] = fmaf(wv, g0.w, a[3]);
            a[4] = fmaf(wv, g1.x, a[4]);
            a[5] = fmaf(wv, g1.y, a[5]);
            a[6] = fmaf(wv, g1.z, a[6]);
            a[7] = fmaf(wv, g1.w, a[7]);
        }
        __syncthreads();
    }

    float* dst = &out[((size_t)b * DQ_ + q) * HW_ + (size_t)hwt * BN3 + hw0];
    f4 o0 = {a[0], a[1], a[2], a[3]};
    f4 o1 = {a[4], a[5], a[6], a[7]};
    *(f4*)dst = o0;
    *(f4*)(dst + 4) = o1;
}

// ============================================================
extern "C" void kernel_launch(void* const* d_in, const int* in_sizes, int n_in,
                              void* d_out, int out_size, void* d_ws, size_t ws_size,
                              hipStream_t stream)
{
    const float* Fp = (const float*)d_in[0];
    const float* Qp = (const float*)d_in[1];
    const float* Wp = (const float*)d_in[2];
    float* out = (float*)d_out;

    const size_t FT_ELEMS = (size_t)B_ * HW_ * C_;
    const size_t W_ELEMS  = (size_t)M_ * C_;
    const size_t PART_OFF = 4 * FT_ELEMS + 4 * W_ELEMS;
    const size_t CODE_WS  = PART_OFF + (size_t)B_ * K_ * NHWT * 4;
    const size_t NEED     = CODE_WS + 128;

    if (ws_size >= NEED) {
        ushort_t* FhiT = (ushort_t*)d_ws;
        ushort_t* FloT = FhiT + FT_ELEMS;
        ushort_t* Whi  = FloT + FT_ELEMS;
        ushort_t* Wlo  = Whi + W_ELEMS;
        float* partial = (float*)((char*)d_ws + PART_OFF);
        int* codes_ws  = (int*)((char*)d_ws + CODE_WS);

        k0_splitF<<<dim3(16, NCT, B_), 256, 0, stream>>>(Fp, FhiT, FloT);
        k0_splitW<<<dim3(W_ELEMS / 1024), 256, 0, stream>>>(Wp, Whi, Wlo);
        k1_mfma8<<<dim3(512), 512, 0, stream>>>(Whi, Wlo, FhiT, FloT, Qp, partial);
        k2_select<<<1, 1024, 0, stream>>>(partial, out, codes_ws);
        k3_mfma<<<dim3(B_ * 16), 256, 0, stream>>>(Whi, Wlo, FhiT, FloT, codes_ws, out);
    } else {
        float* partial = (float*)d_ws;
        int* codes_ws  = (int*)((char*)d_ws + (size_t)B_ * K_ * NHWT * 4);
        k1_dist_fp32<<<dim3(NMT, NHWT, B_), 256, 0, stream>>>(Fp, Qp, Wp, partial);
        k2_select<<<1, 1024, 0, stream>>>(partial, out, codes_ws);
        k3_sel<<<dim3(B_ * 8), 256, 0, stream>>>(Fp, Wp, codes_ws, out);
    }
}